// Round 4
// baseline (1233.547 us; speedup 1.0000x reference)
//
#include <hip/hip_runtime.h>
#include <hip/hip_bf16.h>

typedef _Float16 f16;
typedef __attribute__((ext_vector_type(8))) _Float16 f16x8;
typedef __attribute__((ext_vector_type(4))) float f32x4;
typedef __attribute__((ext_vector_type(4))) unsigned int u32x4;

#define TT 128

__device__ __forceinline__ float sigmoidf_(float x) { return 1.0f / (1.0f + __expf(-x)); }

__device__ __forceinline__ unsigned pack2h_(float a, float b) {
  union { f16 h; unsigned short u; } x, y;
  x.h = (f16)a; y.h = (f16)b;
  return (unsigned)x.u | ((unsigned)y.u << 16);
}

// ---------------------------------------------------------------------------
// fp32 -> fp16 convert (n multiple of 4)
__global__ __launch_bounds__(256) void k_f2h(const float* __restrict__ in,
                                             f16* __restrict__ out, long n4) {
  long i = (long)blockIdx.x * 256 + threadIdx.x;
  if (i >= n4) return;
  float4 v = ((const float4*)in)[i];
  out[i*4+0] = (f16)v.x; out[i*4+1] = (f16)v.y;
  out[i*4+2] = (f16)v.z; out[i*4+3] = (f16)v.w;
}

// gather rule_emb rows for init_prod -> fp16 (32 x 1024)
__global__ __launch_bounds__(256) void k_gather_prod(const float* __restrict__ rule_emb,
                                                     const int* __restrict__ init_prod,
                                                     f16* __restrict__ out) {
  int i = blockIdx.x * 256 + threadIdx.x;
  int b = i >> 10, k = i & 1023;
  out[i] = (f16)rule_emb[(long)init_prod[b] * 1024 + k];
}

// poison n dwords with 0xFFFFFFFF (f16 -NaN halves; tanh path never makes it)
__global__ __launch_bounds__(256) void k_poison(unsigned int* __restrict__ p, long n) {
  long i = (long)blockIdx.x * 256 + threadIdx.x;
  if (i < n) p[i] = 0xFFFFFFFFu;
}

__global__ __launch_bounds__(256) void k_zero(int* __restrict__ p, int n) {
  int i = blockIdx.x * 256 + threadIdx.x;
  if (i < n) p[i] = 0;
}

// h0 -> fp16 into st slot 0. st layout: [t][cg 32][b 32][col 32]
__global__ __launch_bounds__(256) void k_h0(const float* __restrict__ h0,
                                            f16* __restrict__ st) {
  int i = blockIdx.x * 256 + threadIdx.x;
  int b = i >> 10, j = i & 1023;
  st[(long)((j >> 5) * 32 + b) * 32 + (j & 31)] = (f16)h0[i];
}

// (B, L=512, H=1024) fp32 -> outT (B, H, L) f16  AND  outN (B, L, H) f16
__global__ __launch_bounds__(256) void k_transpose(const float* __restrict__ in,
                                                   f16* __restrict__ outT,
                                                   f16* __restrict__ outN) {
  __shared__ float tile[32][33];
  const int b  = blockIdx.z;
  const int l0 = blockIdx.x * 32, h0 = blockIdx.y * 32;
  in   += (long)b * 512 * 1024;
  outT += (long)b * 1024 * 512;
  outN += (long)b * 512 * 1024;
  const int c = threadIdx.x & 31, r = threadIdx.x >> 5;
#pragma unroll
  for (int p = 0; p < 4; ++p) {
    float v = in[(long)(l0 + r + p*8) * 1024 + h0 + c];
    tile[r + p*8][c] = v;
    outN[(long)(l0 + r + p*8) * 1024 + h0 + c] = (f16)v;
  }
  __syncthreads();
#pragma unroll
  for (int p = 0; p < 4; ++p)
    outT[(long)(h0 + r + p*8) * 512 + l0 + c] = (f16)tile[c][r + p*8];
}

// ---------------------------------------------------------------------------
// fp16 MFMA GEMM: C[M,N] = act( A[M,K] @ B[N,K]^T + bias1 + bias2 )
// 128x128 tile, BK=32, register-prefetch double buffer.
// bmod: B K-index wraps mod bmod. zdiv: split-K, partials at outF+slice*sSl.
// ilv: outF column remap col -> (col&1023)*4 + (col>>10)  (gate-interleave).
__global__ __launch_bounds__(256) void k_gemm(
    const f16* __restrict__ A, long lda, long sA,
    const f16* __restrict__ B, long ldb, long sB,
    float* __restrict__ outF, long ldF, long sF, long sSl,
    f16* __restrict__ outH, long ldH, long sH,
    f16* __restrict__ outH2, long ldH2, long sH2,
    f16* __restrict__ out2, long ld2, long s2,
    const float* __restrict__ bias1, const float* __restrict__ bias2,
    int M, int N, int K, int act, int bmod, int zdiv, int ilv)
{
  __shared__ __align__(16) f16 As[128][40];
  __shared__ __align__(16) f16 Bs[128][40];
  const int tid = threadIdx.x;
  const int w = tid >> 6, lane = tid & 63;
  const int wm = (w & 1) * 64, wn = (w >> 1) * 64;
  const int lr = lane >> 4, lc = lane & 15;
  const long m0 = (long)blockIdx.x * 128;
  const long n0 = (long)blockIdx.y * 128;
  int z = blockIdx.z, batch = z, slice = 0, Ks = K;
  if (zdiv > 1) { batch = z / zdiv; slice = z - batch * zdiv; Ks = K / zdiv; }
  const long kbeg = (long)slice * Ks;
  A += (long)batch * sA;
  B += (long)batch * sB;

  const int rr = tid >> 2, sg = (tid & 3) * 8;
  const int nIt = Ks / 32;

  uint4 pa[2], pb[2];
  {
    long k = kbeg;
    long kb = bmod ? (k & (bmod - 1)) : k;
#pragma unroll
    for (int p = 0; p < 2; ++p) {
      int row = p * 64 + rr;
      uint4 va = {0,0,0,0}, vb = {0,0,0,0};
      if (m0 + row < M) va = *(const uint4*)(A + (m0 + row) * lda + k + sg);
      if (n0 + row < N) vb = *(const uint4*)(B + (n0 + row) * ldb + kb + sg);
      pa[p] = va; pb[p] = vb;
    }
  }

  f32x4 acc[4][4];
#pragma unroll
  for (int i = 0; i < 4; ++i)
#pragma unroll
    for (int j = 0; j < 4; ++j) { f32x4 zz = {0.f,0.f,0.f,0.f}; acc[i][j] = zz; }

  for (int it = 0; it < nIt; ++it) {
#pragma unroll
    for (int p = 0; p < 2; ++p) {
      *(uint4*)&As[p * 64 + rr][sg] = pa[p];
      *(uint4*)&Bs[p * 64 + rr][sg] = pb[p];
    }
    __syncthreads();
    if (it + 1 < nIt) {
      long k = kbeg + (long)(it + 1) * 32;
      long kb = bmod ? (k & (bmod - 1)) : k;
#pragma unroll
      for (int p = 0; p < 2; ++p) {
        int row = p * 64 + rr;
        uint4 va = {0,0,0,0}, vb = {0,0,0,0};
        if (m0 + row < M) va = *(const uint4*)(A + (m0 + row) * lda + k + sg);
        if (n0 + row < N) vb = *(const uint4*)(B + (n0 + row) * ldb + kb + sg);
        pa[p] = va; pb[p] = vb;
      }
    }
    f16x8 af[4], bf[4];
#pragma unroll
    for (int i = 0; i < 4; ++i) af[i] = *(const f16x8*)&As[wm + i*16 + lc][lr * 8];
#pragma unroll
    for (int j = 0; j < 4; ++j) bf[j] = *(const f16x8*)&Bs[wn + j*16 + lc][lr * 8];
#pragma unroll
    for (int i = 0; i < 4; ++i)
#pragma unroll
      for (int j = 0; j < 4; ++j)
        acc[i][j] = __builtin_amdgcn_mfma_f32_16x16x32_f16(af[i], bf[j], acc[i][j], 0, 0, 0);
    __syncthreads();
  }

  if (outF)  outF  += (long)batch * sF + (long)slice * sSl;
  if (outH)  outH  += (long)batch * sH;
  if (outH2) outH2 += (long)batch * sH2;
  if (out2)  out2  += (long)batch * s2;
#pragma unroll
  for (int i = 0; i < 4; ++i)
#pragma unroll
    for (int j = 0; j < 4; ++j)
#pragma unroll
      for (int r = 0; r < 4; ++r) {
        long row = m0 + wm + i * 16 + lr * 4 + r;
        long col = n0 + wn + j * 16 + lc;
        if (row < M && col < N) {
          float v = acc[i][j][r];
          if (bias1) v += bias1[col];
          if (bias2) v += bias2[col];
          if (act)   v = tanhf(v);
          if (outF) {
            long fc = ilv ? ((col & 1023) * 4 + (col >> 10)) : col;
            outF[row * ldF + fc] = v;
          }
          if (outH)  outH[row * ldH + col] = (f16)v;
          if (outH2) outH2[row * ldH2 + col] = (f16)v;
          if (out2) {
            f16 hi = (f16)v;
            out2[row * ld2 + col]        = hi;
            out2[row * ld2 + 1024 + col] = (f16)(v - (float)hi);
          }
        }
      }
}

// ---------------------------------------------------------------------------
// Persistent LSTM, minimal-redundancy partition. 64 blocks = 2 batch-groups
// (bg: 16 batches) x 32 col-groups (cg: 32 h-cols = 128 gate rows). 512
// threads = 8 waves; wave wk owns K-chunk [wk*128, wk*128+128).
//
// W_hh slice (128 gate rows x 1024 K, gate-interleaved n = jj*4+g) lives in
// REGISTERS (32 f16x8/lane) -> zero LDS/ds_read on the critical path.
//
// h exchange per step: block reads only ITS 16 batches (32 KB) -> 2 MB/step
// chip-wide (4x less coherent IF traffic than R3's 8 MB). st layout
// [t][cg][b][col]: producer pieces are packed dwords (2 cols), single-writer.
//
// Protocol: flag-as-hint, poison-as-truth. Producer: data dword stores
// (sc0 sc1, fire) -> per-wave flag store (sc0 sc1, fire, NO vmcnt ack).
// Consumer: poll 32 flags (1 dword/lane, coalesced), then load A once and
// verify no 16-bit half is 0xFFFF (f16 -NaN; h=o*tanh(c) is always finite);
// an in-flight flag/data race just retries the data load. st slots 1..128
// re-poisoned each launch (stream-ordered), so stale prior-run data can
// never masquerade as fresh.
__global__ __launch_bounds__(512) void k_lstm_all(
    const f16* __restrict__ Whh,          // (4096,1024) fp16
    const float* __restrict__ nt_table,   // (200,1024,4) gate-interleaved
    const float* __restrict__ prod_gates, // (32,1024,4) gate-interleaved
    const int* __restrict__ nt_ids,       // (128,32)
    const float* __restrict__ c0,         // (32,1024)
    f16* __restrict__ st,                 // (129,32,32,32) [t][cg][b][col]
    f16* __restrict__ q2,                 // (4096,2048) hi|lo
    f16* __restrict__ X,                  // (4096,3072)
    f16* __restrict__ Y1,                 // (4096,2048)
    int* __restrict__ flags)              // (129,32,2,8) [t][cg][bg][wave]
{
  __shared__ float partial[2][8][128][17];
  const int tid = threadIdx.x;
  const int w = tid >> 6, lane = tid & 63;       // wave = K-chunk owner
  const int lr = lane >> 4, lc = lane & 15;
  const int bg = blockIdx.x >> 5;                // batch group (0..1)
  const int cg = blockIdx.x & 31;                // col group  (0..31)

  // ---- W_hh fragments -> registers (step-invariant) ----
  // gate-interleaved local row n = jj*4+g  ->  W_hh row g*1024 + cg*32 + jj
  f16x8 Bf[8][4];
#pragma unroll
  for (int nt = 0; nt < 8; ++nt) {
    int n = nt * 16 + lc;
    const f16* wrow = Whh + (long)((n & 3) * 1024 + cg * 32 + (n >> 2)) * 1024;
#pragma unroll
    for (int kt = 0; kt < 4; ++kt)
      Bf[nt][kt] = *(const f16x8*)(wrow + w * 128 + kt * 32 + lr * 8);
  }

  // ---- cell-phase ownership: one output (b,c) per thread ----
  const int bl = tid >> 5;                 // local batch 0..15
  const int bglob = bg * 16 + bl;          // global batch
  const int c_own = tid & 31;              // local col 0..31
  const int j_own = cg * 32 + c_own;       // global h-col
  float c_reg = c0[(long)bglob * 1024 + j_own];
  float4 pg4 = *(const float4*)(prod_gates + (long)bglob * 4096 + j_own * 4);
  int nid0 = nt_ids[bglob];
  float4 nt4 = *(const float4*)(nt_table + (long)nid0 * 4096 + j_own * 4);

  // ---- consumer addressing ----
  // piece(kt): cg_p = w*4+kt, col0 = lr*8, batch row = bg*16+lc
  const f16* pA0 = st + ((long)(w * 4) * 32 + bg * 16 + lc) * 32 + lr * 8;
  // flags for this wave's 4 producers x 8 waves (lanes 0..31)
  const int* pF = flags + (w * 4 + ((lane >> 3) & 3)) * 16 + bg * 8 + (lane & 7);

  for (int t = 0; t < TT; ++t) {
    // ---- poll producer wave-flags (tiny, coalesced) ----
    if (t > 0) {
      const int* fpt = pF + (long)t * 512;
      int fdone = (lane >= 32);
      while (true) {
        if (!fdone) {
          int fv;
          asm volatile("global_load_dword %0, %1, off sc0 sc1\n\t"
                       "s_waitcnt vmcnt(0)"
                       : "=&v"(fv) : "v"(fpt) : "memory");
          fdone = (fv != 0);
        }
        if (__all(fdone)) break;
        __builtin_amdgcn_s_sleep(1);
      }
    }

    // ---- load A pieces once; poison-verify (retry only on rare race) ----
    u32x4 Ar[4];
    {
      const f16* p0 = pA0 + (long)t * 32768;
      const f16* p2 = p0 + 2048;
      while (true) {
        asm volatile(
          "global_load_dwordx4 %0, %4, off sc0 sc1\n\t"
          "global_load_dwordx4 %1, %4, off offset:2048 sc0 sc1\n\t"
          "global_load_dwordx4 %2, %5, off sc0 sc1\n\t"
          "global_load_dwordx4 %3, %5, off offset:2048 sc0 sc1\n\t"
          "s_waitcnt vmcnt(0)"
          : "=&v"(Ar[0]), "=&v"(Ar[1]), "=&v"(Ar[2]), "=&v"(Ar[3])
          : "v"(p0), "v"(p2) : "memory");
        unsigned mA = 0, mB = 0, mC = 0, mD = 0;
#pragma unroll
        for (int kt = 0; kt < 4; ++kt) {
          asm("v_pk_max_u16 %0, %0, %1" : "+v"(mA) : "v"(Ar[kt].x));
          asm("v_pk_max_u16 %0, %0, %1" : "+v"(mB) : "v"(Ar[kt].y));
          asm("v_pk_max_u16 %0, %0, %1" : "+v"(mC) : "v"(Ar[kt].z));
          asm("v_pk_max_u16 %0, %0, %1" : "+v"(mD) : "v"(Ar[kt].w));
        }
        asm("v_pk_max_u16 %0, %0, %1" : "+v"(mA) : "v"(mB));
        asm("v_pk_max_u16 %0, %0, %1" : "+v"(mC) : "v"(mD));
        asm("v_pk_max_u16 %0, %0, %1" : "+v"(mA) : "v"(mC));
        int ok = !(((mA & 0xFFFFu) == 0xFFFFu) || ((mA >> 16) == 0xFFFFu));
        if (__all(ok)) break;
        __builtin_amdgcn_s_sleep(1);
      }
      __builtin_amdgcn_sched_barrier(0);   // no MFMA hoist above the waitcnt
    }

    // prefetch next step's nt gates (off the critical path)
    float4 nt4n = nt4;
    if (t + 1 < TT) {
      int nidn = nt_ids[(t + 1) * 32 + bglob];
      nt4n = *(const float4*)(nt_table + (long)nidn * 4096 + j_own * 4);
    }

    // ---- MFMA: 1 M-tile x 8 N-tiles x 4 kt ----
    f32x4 acc[8];
#pragma unroll
    for (int nt = 0; nt < 8; ++nt) { f32x4 zz = {0.f,0.f,0.f,0.f}; acc[nt] = zz; }
#pragma unroll
    for (int kt = 0; kt < 4; ++kt) {
      f16x8 av = __builtin_bit_cast(f16x8, Ar[kt]);
#pragma unroll
      for (int nt = 0; nt < 8; ++nt)
        acc[nt] = __builtin_amdgcn_mfma_f32_16x16x32_f16(av, Bf[nt][kt], acc[nt], 0, 0, 0);
    }
    float (*pp)[128][17] = partial[t & 1];
#pragma unroll
    for (int nt = 0; nt < 8; ++nt)
#pragma unroll
      for (int r = 0; r < 4; ++r)
        pp[w][nt * 16 + lc][lr * 4 + r] = acc[nt][r];
    __syncthreads();

    // ---- reduce 8 K-slices + LSTM cell (one output per thread) ----
    float g4[4] = {0.f, 0.f, 0.f, 0.f};
#pragma unroll
    for (int w8 = 0; w8 < 8; ++w8)
#pragma unroll
      for (int g = 0; g < 4; ++g)
        g4[g] += pp[w8][c_own * 4 + g][bl];

    float ii = sigmoidf_(g4[0] + nt4.x + pg4.x);
    float ff = sigmoidf_(g4[1] + nt4.y + pg4.y);
    float gg = tanhf(g4[2] + nt4.z + pg4.z);
    float oo = sigmoidf_(g4[3] + nt4.w + pg4.w);
    c_reg = ff * c_reg + ii * gg;
    float hn = oo * tanhf(c_reg);
    f16 hi = (f16)hn;
    float lo_f = hn - (float)hi;

    // pair-pack (c even holds c, c+1) via lane shuffle
    float hn1 = __shfl_down(hn, 1);
    float lo1 = __shfl_down(lo_f, 1);

    // ---- publish h_{t+1}: packed dwords, fire-and-forget; then wave-flag ----
    if (t + 1 < TT) {
      if (!(tid & 1)) {
        unsigned pay = pack2h_(hn, hn1);
        f16* pst = st + ((long)((t + 1) * 32 + cg) * 32 + bglob) * 32 + c_own;
        asm volatile("global_store_dword %0, %1, off sc0 sc1"
                     :: "v"(pst), "v"(pay) : "memory");
      }
      if (lane == 0) {
        int* pf = flags + ((long)(t + 1) * 32 + cg) * 16 + bg * 8 + w;
        int one = 1;
        asm volatile("global_store_dword %0, %1, off sc0 sc1"
                     :: "v"(pf), "v"(one) : "memory");
      }
    }

    // ---- non-critical stores (consumed post-kernel): cached, packed ----
    if (!(tid & 1)) {
      long row = (long)bglob * 128 + t;
      *(unsigned*)&q2[row * 2048 + j_own]        = pack2h_(hn, hn1);
      *(unsigned*)&q2[row * 2048 + 1024 + j_own] = pack2h_(lo_f, lo1);
      *(unsigned*)&X[row * 3072 + j_own]         = pack2h_(hn, hn1);
      *(unsigned*)&Y1[row * 2048 + 1024 + j_own] = pack2h_(hn, hn1);
    }

    nt4 = nt4n;
  }
}

// ---------------------------------------------------------------------------
// Row softmax over 512 cols of sum of 4 fp32 planes -> fp16. One block/row.
__global__ __launch_bounds__(256) void k_softmax4(const float* __restrict__ p,
                                                  long pstride,
                                                  f16* __restrict__ out) {
  long row = blockIdx.x;
  const float* p0 = p + row * 512;
  out += row * 512;
  const int tid = threadIdx.x, w = tid >> 6, lane = tid & 63;
  float vx = 0.f, vy = 0.f;
#pragma unroll
  for (int s = 0; s < 4; ++s) {
    float2 a = ((const float2*)(p0 + s * pstride))[tid];
    vx += a.x; vy += a.y;
  }
  float m = fmaxf(vx, vy);
#pragma unroll
  for (int off = 32; off; off >>= 1) m = fmaxf(m, __shfl_xor(m, off));
  __shared__ float red[8];
  if (lane == 0) red[w] = m;
  __syncthreads();
  m = fmaxf(fmaxf(red[0], red[1]), fmaxf(red[2], red[3]));
  float e0 = __expf(vx - m), e1 = __expf(vy - m);
  float s2 = e0 + e1;
#pragma unroll
  for (int off = 32; off; off >>= 1) s2 += __shfl_xor(s2, off);
  if (lane == 0) red[4 + w] = s2;
  __syncthreads();
  s2 = red[4] + red[5] + red[6] + red[7];
  float inv = 1.0f / s2;
  out[tid * 2]     = (f16)(e0 * inv);
  out[tid * 2 + 1] = (f16)(e1 * inv);
}

// ---------------------------------------------------------------------------
extern "C" void kernel_launch(void* const* d_in, const int* in_sizes, int n_in,
                              void* d_out, int out_size, void* d_ws, size_t ws_size,
                              hipStream_t stream)
{
  const int*   init_prod = (const int*)d_in[0];
  const int*   nt_ids    = (const int*)d_in[1];
  const float* h0   = (const float*)d_in[2];
  const float* c0   = (const float*)d_in[3];
  const float* nl   = (const float*)d_in[4];
  const float* env  = (const float*)d_in[5];
  const float* nt_emb   = (const float*)d_in[6];
  const float* rule_emb = (const float*)d_in[7];
  const float* W_ih = (const float*)d_in[8];
  const float* W_hh = (const float*)d_in[9];
  const float* b_ih = (const float*)d_in[10];
  const float* b_hh = (const float*)d_in[11];
  const float* Wz   = (const float*)d_in[12];
  const float* bz   = (const float*)d_in[13];
  const float* We   = (const float*)d_in[14];
  const float* be   = (const float*)d_in[15];
  const float* Wc   = (const float*)d_in[16];
  const float* bc   = (const float*)d_in[17];
  float* out = (float*)d_out;
  (void)in_sizes; (void)n_in; (void)out_size; (void)ws_size;

  size_t off = 0;
  auto carve = [&](size_t bytes) {
    char* p = (char*)d_ws + off;
    off += (bytes + 255) & ~(size_t)255;
    return (void*)p;
  };
  f16*   Whh_h   = (f16*)carve(4096L * 1024 * 2);
  f16*   Wz_h    = (f16*)carve(1024L * 2048 * 2);
  f16*   We_h    = (f16*)carve(1024L * 2048 * 2);
  f16*   Wc_h    = (f16*)carve(1024L * 3072 * 2);
  f16*   nte_h   = (f16*)carve(200L * 1024 * 2);
  f16*   prod_h  = (f16*)carve(32L * 1024 * 2);
  float* nt_table   = (float*)carve(200L * 4096 * 4);   // gate-interleaved
  float* prod_gates = (float*)carve(32L * 4096 * 4);    // gate-interleaved
  f16*   st_hi   = (f16*)carve(129L * 32 * 32 * 32 * 2);  // [t][cg][b][col]
  f16*   q2      = (f16*)carve(4096L * 2048 * 2);   // query hi|lo (h, then zt)
  f16*   X       = (f16*)carve(4096L * 3072 * 2);   // [h | zt | et] for ct GEMM
  f16*   Y1      = (f16*)carve(4096L * 2048 * 2);   // [mix1 | h]  for zt GEMM
  f16*   Y2      = (f16*)carve(4096L * 2048 * 2);   // [mix2 | zt] for et GEMM
  f16*   ctx_h   = (f16*)carve(32L * 512 * 1024 * 2);
  f16*   ctxT    = (f16*)carve(32L * 1024 * 512 * 2);
  float* scoresP = (float*)carve(4L * 32 * 128 * 512 * 4);  // 4 split-K planes
  f16*   attn    = (f16*)carve(4096L * 512 * 2);
  int*   bar     = (int*)carve(129L * 512 * 4);   // flags [t][cg][bg][wave]
  f16*   Wih_h   = (f16*)X;   // alias: Wih dead before LSTM writes X

  auto f2h = [&](const float* src, f16* dst, long n) {
    long n4 = n / 4;
    k_f2h<<<dim3((unsigned)((n4 + 255) / 256)), dim3(256), 0, stream>>>(src, dst, n4);
  };
  f2h(W_ih, Wih_h, 4096L * 2048);
  f2h(W_hh, Whh_h, 4096L * 1024);
  f2h(Wz,   Wz_h,  1024L * 2048);
  f2h(We,   We_h,  1024L * 2048);
  f2h(Wc,   Wc_h,  1024L * 3072);
  f2h(nt_emb, nte_h, 200L * 1024);
  k_gather_prod<<<dim3(128), dim3(256), 0, stream>>>(rule_emb, init_prod, prod_h);
  // poison h slots 1..128, write h0 into slot 0, zero flags (stream-ordered)
  k_poison<<<dim3(8192), dim3(256), 0, stream>>>(
      (unsigned int*)st_hi + 16384, 128L * 16384);
  k_h0<<<dim3(128), dim3(256), 0, stream>>>(h0, st_hi);
  k_zero<<<dim3(259), dim3(256), 0, stream>>>(bar, 129 * 512);

  auto gemm = [&](const f16* A, long lda, long sA,
                  const f16* B, long ldb, long sB,
                  float* oF, long ldF, long sF, long sSl,
                  f16* oH, long ldH, long sH,
                  f16* oH2, long ldH2, long sH2,
                  f16* o2, long ld2, long s2,
                  const float* b1, const float* b2,
                  int M, int N, int K, int act, int bmod, int zdiv, int ilv,
                  int batch) {
    dim3 grid((unsigned)((M + 127) / 128), (unsigned)((N + 127) / 128),
              (unsigned)(batch * zdiv));
    k_gemm<<<grid, dim3(256), 0, stream>>>(A, lda, sA, B, ldb, sB,
                                           oF, ldF, sF, sSl, oH, ldH, sH,
                                           oH2, ldH2, sH2, o2, ld2, s2,
                                           b1, b2, M, N, K, act, bmod, zdiv, ilv);
  };
  const long SPL = 32L * 128 * 512;   // split-K plane stride (floats)

  // gate tables (gate-interleaved fp32 layout via ilv=1)
  gemm(nte_h, 1024, 0, Wih_h, 2048, 0, nt_table, 4096, 0, 0,
       nullptr,0,0, nullptr,0,0, nullptr,0,0, nullptr, nullptr,
       200, 4096, 1024, 0, 0, 1, 1, 1);
  gemm(prod_h, 1024, 0, Wih_h + 1024, 2048, 0, prod_gates, 4096, 0, 0,
       nullptr,0,0, nullptr,0,0, nullptr,0,0, b_ih, b_hh,
       32, 4096, 1024, 0, 0, 1, 1, 1);

  // persistent LSTM: 64 blocks x 512 threads, flag-hint + poison-truth
  k_lstm_all<<<dim3(64), dim3(512), 0, stream>>>(
      Whh_h, nt_table, prod_gates, nt_ids, c0, st_hi, q2, X, Y1, bar);

  // --- attention over nl ---
  k_transpose<<<dim3(16, 32, 32), dim3(256), 0, stream>>>(nl, ctxT, ctx_h);
  gemm(q2, 2048, 128L * 2048, ctx_h, 1024, 512L * 1024,
       scoresP, 512, 128L * 512, SPL, nullptr,0,0, nullptr,0,0, nullptr,0,0,
       nullptr, nullptr, 128, 512, 2048, 0, 1024, 4, 0, 32);
  k_softmax4<<<dim3(4096), dim3(256), 0, stream>>>(scoresP, SPL, attn);
  gemm(attn, 512, 128L * 512, ctxT, 512, 1024L * 512,
       nullptr,0,0,0, Y1, 2048, 128L * 2048, nullptr,0,0, nullptr,0,0,
       nullptr, nullptr, 128, 1024, 512, 0, 0, 1, 0, 32);
  // zt = tanh(Y1=[mix1|h] @ Wz^T + bz) -> X[:,1024:2048), Y2[:,1024:2048), q2
  gemm(Y1, 2048, 0, Wz_h, 2048, 0,
       nullptr,0,0,0, X + 1024, 3072, 0, Y2 + 1024, 2048, 0, q2, 2048, 0,
       bz, nullptr, 4096, 1024, 2048, 1, 0, 1, 0, 1);

  // --- attention over env ---
  k_transpose<<<dim3(16, 32, 32), dim3(256), 0, stream>>>(env, ctxT, ctx_h);
  gemm(q2, 2048, 128L * 2048, ctx_h, 1024, 512L * 1024,
       scoresP, 512, 128L * 512, SPL, nullptr,0,0, nullptr,0,0, nullptr,0,0,
       nullptr, nullptr, 128, 512, 2048, 0, 1024, 4, 0, 32);
  k_softmax4<<<dim3(4096), dim3(256), 0, stream>>>(scoresP, SPL, attn);
  gemm(attn, 512, 128L * 512, ctxT, 512, 1024L * 512,
       nullptr,0,0,0, Y2, 2048, 128L * 2048, nullptr,0,0, nullptr,0,0,
       nullptr, nullptr, 128, 1024, 512, 0, 0, 1, 0, 32);
  // et = tanh(Y2=[mix2|zt] @ We^T + be) -> X[:,2048:3072)
  gemm(Y2, 2048, 0, We_h, 2048, 0,
       nullptr,0,0,0, X + 2048, 3072, 0, nullptr,0,0, nullptr,0,0,
       be, nullptr, 4096, 1024, 2048, 1, 0, 1, 0, 1);

  // --- ct = tanh(X=[h|zt|et] @ Wc^T + bc) -> d_out (T,B,H) ---
  gemm(X, 3072, 128L * 3072, Wc_h, 3072, 0,
       out, 32L * 1024, 1024, 0, nullptr,0,0, nullptr,0,0, nullptr,0,0,
       bc, nullptr, 128, 1024, 3072, 1, 0, 1, 0, 32);
}

// Round 5
// 1166.893 us; speedup vs baseline: 1.0571x; 1.0571x over previous
//
#include <hip/hip_runtime.h>
#include <hip/hip_bf16.h>

typedef _Float16 f16;
typedef __attribute__((ext_vector_type(8))) _Float16 f16x8;
typedef __attribute__((ext_vector_type(4))) float f32x4;
typedef __attribute__((ext_vector_type(4))) unsigned int u32x4;

#define TT 128

__device__ __forceinline__ float sigmoidf_(float x) { return 1.0f / (1.0f + __expf(-x)); }

__device__ __forceinline__ unsigned pack2h_(float a, float b) {
  union { f16 h; unsigned short u; } x, y;
  x.h = (f16)a; y.h = (f16)b;
  return (unsigned)x.u | ((unsigned)y.u << 16);
}

// ---------------------------------------------------------------------------
// fp32 -> fp16 convert (n multiple of 4)
__global__ __launch_bounds__(256) void k_f2h(const float* __restrict__ in,
                                             f16* __restrict__ out, long n4) {
  long i = (long)blockIdx.x * 256 + threadIdx.x;
  if (i >= n4) return;
  float4 v = ((const float4*)in)[i];
  out[i*4+0] = (f16)v.x; out[i*4+1] = (f16)v.y;
  out[i*4+2] = (f16)v.z; out[i*4+3] = (f16)v.w;
}

// gather rule_emb rows for init_prod -> fp16 (32 x 1024)
__global__ __launch_bounds__(256) void k_gather_prod(const float* __restrict__ rule_emb,
                                                     const int* __restrict__ init_prod,
                                                     f16* __restrict__ out) {
  int i = blockIdx.x * 256 + threadIdx.x;
  int b = i >> 10, k = i & 1023;
  out[i] = (f16)rule_emb[(long)init_prod[b] * 1024 + k];
}

// poison n dwords with 0xFFFFFFFF (f16 -NaN halves; tanh path never makes it)
__global__ __launch_bounds__(256) void k_poison(unsigned int* __restrict__ p, long n) {
  long i = (long)blockIdx.x * 256 + threadIdx.x;
  if (i < n) p[i] = 0xFFFFFFFFu;
}

__global__ __launch_bounds__(256) void k_zero(int* __restrict__ p, int n) {
  int i = blockIdx.x * 256 + threadIdx.x;
  if (i < n) p[i] = 0;
}

// h0 -> fp16 into st slot 0. st layout: [t][cg 32][b 32][col 32]
__global__ __launch_bounds__(256) void k_h0(const float* __restrict__ h0,
                                            f16* __restrict__ st) {
  int i = blockIdx.x * 256 + threadIdx.x;
  int b = i >> 10, j = i & 1023;
  st[(long)((j >> 5) * 32 + b) * 32 + (j & 31)] = (f16)h0[i];
}

// (B, L=512, H=1024) fp32 -> outT (B, H, L) f16  AND  outN (B, L, H) f16
__global__ __launch_bounds__(256) void k_transpose(const float* __restrict__ in,
                                                   f16* __restrict__ outT,
                                                   f16* __restrict__ outN) {
  __shared__ float tile[32][33];
  const int b  = blockIdx.z;
  const int l0 = blockIdx.x * 32, h0 = blockIdx.y * 32;
  in   += (long)b * 512 * 1024;
  outT += (long)b * 1024 * 512;
  outN += (long)b * 512 * 1024;
  const int c = threadIdx.x & 31, r = threadIdx.x >> 5;
#pragma unroll
  for (int p = 0; p < 4; ++p) {
    float v = in[(long)(l0 + r + p*8) * 1024 + h0 + c];
    tile[r + p*8][c] = v;
    outN[(long)(l0 + r + p*8) * 1024 + h0 + c] = (f16)v;
  }
  __syncthreads();
#pragma unroll
  for (int p = 0; p < 4; ++p)
    outT[(long)(h0 + r + p*8) * 512 + l0 + c] = (f16)tile[c][r + p*8];
}

// ---------------------------------------------------------------------------
// fp16 MFMA GEMM: C[M,N] = act( A[M,K] @ B[N,K]^T + bias1 + bias2 )
// 128x128 tile, BK=32, register-prefetch double buffer.
// bmod: B K-index wraps mod bmod. zdiv: split-K, partials at outF+slice*sSl.
// ilv: outF column remap col -> (col&1023)*4 + (col>>10)  (gate-interleave).
__global__ __launch_bounds__(256) void k_gemm(
    const f16* __restrict__ A, long lda, long sA,
    const f16* __restrict__ B, long ldb, long sB,
    float* __restrict__ outF, long ldF, long sF, long sSl,
    f16* __restrict__ outH, long ldH, long sH,
    f16* __restrict__ outH2, long ldH2, long sH2,
    f16* __restrict__ out2, long ld2, long s2,
    const float* __restrict__ bias1, const float* __restrict__ bias2,
    int M, int N, int K, int act, int bmod, int zdiv, int ilv)
{
  __shared__ __align__(16) f16 As[128][40];
  __shared__ __align__(16) f16 Bs[128][40];
  const int tid = threadIdx.x;
  const int w = tid >> 6, lane = tid & 63;
  const int wm = (w & 1) * 64, wn = (w >> 1) * 64;
  const int lr = lane >> 4, lc = lane & 15;
  const long m0 = (long)blockIdx.x * 128;
  const long n0 = (long)blockIdx.y * 128;
  int z = blockIdx.z, batch = z, slice = 0, Ks = K;
  if (zdiv > 1) { batch = z / zdiv; slice = z - batch * zdiv; Ks = K / zdiv; }
  const long kbeg = (long)slice * Ks;
  A += (long)batch * sA;
  B += (long)batch * sB;

  const int rr = tid >> 2, sg = (tid & 3) * 8;
  const int nIt = Ks / 32;

  uint4 pa[2], pb[2];
  {
    long k = kbeg;
    long kb = bmod ? (k & (bmod - 1)) : k;
#pragma unroll
    for (int p = 0; p < 2; ++p) {
      int row = p * 64 + rr;
      uint4 va = {0,0,0,0}, vb = {0,0,0,0};
      if (m0 + row < M) va = *(const uint4*)(A + (m0 + row) * lda + k + sg);
      if (n0 + row < N) vb = *(const uint4*)(B + (n0 + row) * ldb + kb + sg);
      pa[p] = va; pb[p] = vb;
    }
  }

  f32x4 acc[4][4];
#pragma unroll
  for (int i = 0; i < 4; ++i)
#pragma unroll
    for (int j = 0; j < 4; ++j) { f32x4 zz = {0.f,0.f,0.f,0.f}; acc[i][j] = zz; }

  for (int it = 0; it < nIt; ++it) {
#pragma unroll
    for (int p = 0; p < 2; ++p) {
      *(uint4*)&As[p * 64 + rr][sg] = pa[p];
      *(uint4*)&Bs[p * 64 + rr][sg] = pb[p];
    }
    __syncthreads();
    if (it + 1 < nIt) {
      long k = kbeg + (long)(it + 1) * 32;
      long kb = bmod ? (k & (bmod - 1)) : k;
#pragma unroll
      for (int p = 0; p < 2; ++p) {
        int row = p * 64 + rr;
        uint4 va = {0,0,0,0}, vb = {0,0,0,0};
        if (m0 + row < M) va = *(const uint4*)(A + (m0 + row) * lda + k + sg);
        if (n0 + row < N) vb = *(const uint4*)(B + (n0 + row) * ldb + kb + sg);
        pa[p] = va; pb[p] = vb;
      }
    }
    f16x8 af[4], bf[4];
#pragma unroll
    for (int i = 0; i < 4; ++i) af[i] = *(const f16x8*)&As[wm + i*16 + lc][lr * 8];
#pragma unroll
    for (int j = 0; j < 4; ++j) bf[j] = *(const f16x8*)&Bs[wn + j*16 + lc][lr * 8];
#pragma unroll
    for (int i = 0; i < 4; ++i)
#pragma unroll
      for (int j = 0; j < 4; ++j)
        acc[i][j] = __builtin_amdgcn_mfma_f32_16x16x32_f16(af[i], bf[j], acc[i][j], 0, 0, 0);
    __syncthreads();
  }

  if (outF)  outF  += (long)batch * sF + (long)slice * sSl;
  if (outH)  outH  += (long)batch * sH;
  if (outH2) outH2 += (long)batch * sH2;
  if (out2)  out2  += (long)batch * s2;
#pragma unroll
  for (int i = 0; i < 4; ++i)
#pragma unroll
    for (int j = 0; j < 4; ++j)
#pragma unroll
      for (int r = 0; r < 4; ++r) {
        long row = m0 + wm + i * 16 + lr * 4 + r;
        long col = n0 + wn + j * 16 + lc;
        if (row < M && col < N) {
          float v = acc[i][j][r];
          if (bias1) v += bias1[col];
          if (bias2) v += bias2[col];
          if (act)   v = tanhf(v);
          if (outF) {
            long fc = ilv ? ((col & 1023) * 4 + (col >> 10)) : col;
            outF[row * ldF + fc] = v;
          }
          if (outH)  outH[row * ldH + col] = (f16)v;
          if (outH2) outH2[row * ldH2 + col] = (f16)v;
          if (out2) {
            f16 hi = (f16)v;
            out2[row * ld2 + col]        = hi;
            out2[row * ld2 + 1024 + col] = (f16)(v - (float)hi);
          }
        }
      }
}

// ---------------------------------------------------------------------------
// Persistent LSTM, minimal-redundancy partition (R4 geometry, fixed impl).
// 64 blocks = 2 batch-groups (16 batches) x 32 col-groups (32 h-cols = 128
// gate rows). 512 threads = 8 waves; wave w owns K-chunk [w*128, +128).
//
// Fix 1 (R4 failure): __launch_bounds__(512, 2). LDS (132 KB) caps occupancy
// at 1 block/CU = 2 waves/SIMD anyway; without the ",2" the compiler capped
// VGPRs at 112 for an unreachable 4 waves/SIMD and spilled/rematerialized
// Bf[8][4] (128 VGPR) -> W_hh was re-fetched from L2 every step. Now the
// 256-VGPR budget holds the whole W_hh slice in registers.
//
// Fix 2: partial layout [buf][w][g][m 16][c 32+1pad]: both the MFMA-side
// write (pp[w][lc&3][lr*4+r][nt*4+(lc>>2)]) and the reduce-side read
// (pp[w8][g][bl][c_own], lane-stride 1) are <=2 lanes/bank (free).
//
// Fix 3: producer orders data ahead of flag again: data stores (sc0 sc1) ->
// s_waitcnt vmcnt(0) (ack = at coherence point) -> wave flag. Poison check
// on the consumer stays as a (never-taken) safety net.
__global__ __launch_bounds__(512, 2) void k_lstm_all(
    const f16* __restrict__ Whh,          // (4096,1024) fp16
    const float* __restrict__ nt_table,   // (200,1024,4) gate-interleaved
    const float* __restrict__ prod_gates, // (32,1024,4) gate-interleaved
    const int* __restrict__ nt_ids,       // (128,32)
    const float* __restrict__ c0,         // (32,1024)
    f16* __restrict__ st,                 // (129,32,32,32) [t][cg][b][col]
    f16* __restrict__ q2,                 // (4096,2048) hi|lo
    f16* __restrict__ X,                  // (4096,3072)
    f16* __restrict__ Y1,                 // (4096,2048)
    int* __restrict__ flags)              // (129,32,2,8) [t][cg][bg][wave]
{
  __shared__ float partial[2][8][4][16][33];
  const int tid = threadIdx.x;
  const int w = tid >> 6, lane = tid & 63;       // wave = K-chunk owner
  const int lr = lane >> 4, lc = lane & 15;
  const int bg = blockIdx.x >> 5;                // batch group (0..1)
  const int cg = blockIdx.x & 31;                // col group  (0..31)

  // ---- W_hh fragments -> registers (step-invariant) ----
  // gate-interleaved local row n = jj*4+g  ->  W_hh row g*1024 + cg*32 + jj
  f16x8 Bf[8][4];
#pragma unroll
  for (int nt = 0; nt < 8; ++nt) {
    int n = nt * 16 + lc;
    const f16* wrow = Whh + (long)((n & 3) * 1024 + cg * 32 + (n >> 2)) * 1024;
#pragma unroll
    for (int kt = 0; kt < 4; ++kt)
      Bf[nt][kt] = *(const f16x8*)(wrow + w * 128 + kt * 32 + lr * 8);
  }

  // ---- cell-phase ownership: one output (b,c) per thread ----
  const int bl = tid >> 5;                 // local batch 0..15
  const int bglob = bg * 16 + bl;          // global batch
  const int c_own = tid & 31;              // local col 0..31
  const int j_own = cg * 32 + c_own;       // global h-col
  float c_reg = c0[(long)bglob * 1024 + j_own];
  float4 pg4 = *(const float4*)(prod_gates + (long)bglob * 4096 + j_own * 4);
  int nid0 = nt_ids[bglob];
  float4 nt4 = *(const float4*)(nt_table + (long)nid0 * 4096 + j_own * 4);

  // ---- consumer addressing ----
  // piece(kt): cg_p = w*4+kt, col0 = lr*8, batch row = bg*16+lc
  const f16* pA0 = st + ((long)(w * 4) * 32 + bg * 16 + lc) * 32 + lr * 8;
  // flags of this wave's 4 producers x 8 waves (lanes 0..31)
  const int* pF = flags + (w * 4 + ((lane >> 3) & 3)) * 16 + bg * 8 + (lane & 7);

  for (int t = 0; t < TT; ++t) {
    // ---- poll producer wave-flags (tiny, coalesced) ----
    if (t > 0) {
      const int* fpt = pF + (long)t * 512;
      int fdone = (lane >= 32);
      while (true) {
        if (!fdone) {
          int fv;
          asm volatile("global_load_dword %0, %1, off sc0 sc1\n\t"
                       "s_waitcnt vmcnt(0)"
                       : "=&v"(fv) : "v"(fpt) : "memory");
          fdone = (fv != 0);
        }
        if (__all(fdone)) break;
        __builtin_amdgcn_s_sleep(1);
      }
    }

    // ---- load A pieces once; poison-verify (safety net, never taken) ----
    u32x4 Ar[4];
    {
      const f16* p0 = pA0 + (long)t * 32768;
      const f16* p2 = p0 + 2048;
      while (true) {
        asm volatile(
          "global_load_dwordx4 %0, %4, off sc0 sc1\n\t"
          "global_load_dwordx4 %1, %4, off offset:2048 sc0 sc1\n\t"
          "global_load_dwordx4 %2, %5, off sc0 sc1\n\t"
          "global_load_dwordx4 %3, %5, off offset:2048 sc0 sc1\n\t"
          "s_waitcnt vmcnt(0)"
          : "=&v"(Ar[0]), "=&v"(Ar[1]), "=&v"(Ar[2]), "=&v"(Ar[3])
          : "v"(p0), "v"(p2) : "memory");
        unsigned mA = 0, mB = 0, mC = 0, mD = 0;
#pragma unroll
        for (int kt = 0; kt < 4; ++kt) {
          asm("v_pk_max_u16 %0, %0, %1" : "+v"(mA) : "v"(Ar[kt].x));
          asm("v_pk_max_u16 %0, %0, %1" : "+v"(mB) : "v"(Ar[kt].y));
          asm("v_pk_max_u16 %0, %0, %1" : "+v"(mC) : "v"(Ar[kt].z));
          asm("v_pk_max_u16 %0, %0, %1" : "+v"(mD) : "v"(Ar[kt].w));
        }
        asm("v_pk_max_u16 %0, %0, %1" : "+v"(mA) : "v"(mB));
        asm("v_pk_max_u16 %0, %0, %1" : "+v"(mC) : "v"(mD));
        asm("v_pk_max_u16 %0, %0, %1" : "+v"(mA) : "v"(mC));
        int ok = !(((mA & 0xFFFFu) == 0xFFFFu) || ((mA >> 16) == 0xFFFFu));
        if (__all(ok)) break;
        __builtin_amdgcn_s_sleep(1);
      }
      __builtin_amdgcn_sched_barrier(0);   // no MFMA hoist above the waitcnt
    }

    // prefetch next step's nt gates (off the critical path)
    float4 nt4n = nt4;
    if (t + 1 < TT) {
      int nidn = nt_ids[(t + 1) * 32 + bglob];
      nt4n = *(const float4*)(nt_table + (long)nidn * 4096 + j_own * 4);
    }

    // ---- MFMA: 1 M-tile x 8 N-tiles x 4 kt ----
    f32x4 acc[8];
#pragma unroll
    for (int nt = 0; nt < 8; ++nt) { f32x4 zz = {0.f,0.f,0.f,0.f}; acc[nt] = zz; }
#pragma unroll
    for (int kt = 0; kt < 4; ++kt) {
      f16x8 av = __builtin_bit_cast(f16x8, Ar[kt]);
#pragma unroll
      for (int nt = 0; nt < 8; ++nt)
        acc[nt] = __builtin_amdgcn_mfma_f32_16x16x32_f16(av, Bf[nt][kt], acc[nt], 0, 0, 0);
    }
    // write: n = nt*16+lc -> (g = lc&3, c_local = nt*4 + (lc>>2)); m = lr*4+r
    float (*pp)[4][16][33] = partial[t & 1];
#pragma unroll
    for (int nt = 0; nt < 8; ++nt)
#pragma unroll
      for (int r = 0; r < 4; ++r)
        pp[w][lc & 3][lr * 4 + r][nt * 4 + (lc >> 2)] = acc[nt][r];
    __syncthreads();

    // ---- reduce 8 K-slices + LSTM cell (one output per thread) ----
    float g4[4] = {0.f, 0.f, 0.f, 0.f};
#pragma unroll
    for (int w8 = 0; w8 < 8; ++w8)
#pragma unroll
      for (int g = 0; g < 4; ++g)
        g4[g] += pp[w8][g][bl][c_own];

    float ii = sigmoidf_(g4[0] + nt4.x + pg4.x);
    float ff = sigmoidf_(g4[1] + nt4.y + pg4.y);
    float gg = tanhf(g4[2] + nt4.z + pg4.z);
    float oo = sigmoidf_(g4[3] + nt4.w + pg4.w);
    c_reg = ff * c_reg + ii * gg;
    float hn = oo * tanhf(c_reg);
    f16 hi = (f16)hn;
    float lo_f = hn - (float)hi;

    // pair-pack (even c holds c, c+1) via lane shuffle
    float hn1 = __shfl_down(hn, 1);
    float lo1 = __shfl_down(lo_f, 1);

    // ---- publish h_{t+1}: data -> vmcnt ack -> wave flag ----
    if (t + 1 < TT) {
      if (!(tid & 1)) {
        unsigned pay = pack2h_(hn, hn1);
        f16* pst = st + ((long)((t + 1) * 32 + cg) * 32 + bglob) * 32 + c_own;
        asm volatile("global_store_dword %0, %1, off sc0 sc1"
                     :: "v"(pst), "v"(pay) : "memory");
      }
      asm volatile("s_waitcnt vmcnt(0)" ::: "memory");   // data at coherence pt
      if (lane == 0) {
        int* pf = flags + ((long)(t + 1) * 32 + cg) * 16 + bg * 8 + w;
        int one = 1;
        asm volatile("global_store_dword %0, %1, off sc0 sc1"
                     :: "v"(pf), "v"(one) : "memory");
      }
    }

    // ---- non-critical stores (consumed post-kernel): cached, packed ----
    if (!(tid & 1)) {
      long row = (long)bglob * 128 + t;
      *(unsigned*)&q2[row * 2048 + j_own]        = pack2h_(hn, hn1);
      *(unsigned*)&q2[row * 2048 + 1024 + j_own] = pack2h_(lo_f, lo1);
      *(unsigned*)&X[row * 3072 + j_own]         = pack2h_(hn, hn1);
      *(unsigned*)&Y1[row * 2048 + 1024 + j_own] = pack2h_(hn, hn1);
    }

    nt4 = nt4n;
  }
}

// ---------------------------------------------------------------------------
// Row softmax over 512 cols of sum of 4 fp32 planes -> fp16. One block/row.
__global__ __launch_bounds__(256) void k_softmax4(const float* __restrict__ p,
                                                  long pstride,
                                                  f16* __restrict__ out) {
  long row = blockIdx.x;
  const float* p0 = p + row * 512;
  out += row * 512;
  const int tid = threadIdx.x, w = tid >> 6, lane = tid & 63;
  float vx = 0.f, vy = 0.f;
#pragma unroll
  for (int s = 0; s < 4; ++s) {
    float2 a = ((const float2*)(p0 + s * pstride))[tid];
    vx += a.x; vy += a.y;
  }
  float m = fmaxf(vx, vy);
#pragma unroll
  for (int off = 32; off; off >>= 1) m = fmaxf(m, __shfl_xor(m, off));
  __shared__ float red[8];
  if (lane == 0) red[w] = m;
  __syncthreads();
  m = fmaxf(fmaxf(red[0], red[1]), fmaxf(red[2], red[3]));
  float e0 = __expf(vx - m), e1 = __expf(vy - m);
  float s2 = e0 + e1;
#pragma unroll
  for (int off = 32; off; off >>= 1) s2 += __shfl_xor(s2, off);
  if (lane == 0) red[4 + w] = s2;
  __syncthreads();
  s2 = red[4] + red[5] + red[6] + red[7];
  float inv = 1.0f / s2;
  out[tid * 2]     = (f16)(e0 * inv);
  out[tid * 2 + 1] = (f16)(e1 * inv);
}

// ---------------------------------------------------------------------------
extern "C" void kernel_launch(void* const* d_in, const int* in_sizes, int n_in,
                              void* d_out, int out_size, void* d_ws, size_t ws_size,
                              hipStream_t stream)
{
  const int*   init_prod = (const int*)d_in[0];
  const int*   nt_ids    = (const int*)d_in[1];
  const float* h0   = (const float*)d_in[2];
  const float* c0   = (const float*)d_in[3];
  const float* nl   = (const float*)d_in[4];
  const float* env  = (const float*)d_in[5];
  const float* nt_emb   = (const float*)d_in[6];
  const float* rule_emb = (const float*)d_in[7];
  const float* W_ih = (const float*)d_in[8];
  const float* W_hh = (const float*)d_in[9];
  const float* b_ih = (const float*)d_in[10];
  const float* b_hh = (const float*)d_in[11];
  const float* Wz   = (const float*)d_in[12];
  const float* bz   = (const float*)d_in[13];
  const float* We   = (const float*)d_in[14];
  const float* be   = (const float*)d_in[15];
  const float* Wc   = (const float*)d_in[16];
  const float* bc   = (const float*)d_in[17];
  float* out = (float*)d_out;
  (void)in_sizes; (void)n_in; (void)out_size; (void)ws_size;

  size_t off = 0;
  auto carve = [&](size_t bytes) {
    char* p = (char*)d_ws + off;
    off += (bytes + 255) & ~(size_t)255;
    return (void*)p;
  };
  f16*   Whh_h   = (f16*)carve(4096L * 1024 * 2);
  f16*   Wz_h    = (f16*)carve(1024L * 2048 * 2);
  f16*   We_h    = (f16*)carve(1024L * 2048 * 2);
  f16*   Wc_h    = (f16*)carve(1024L * 3072 * 2);
  f16*   nte_h   = (f16*)carve(200L * 1024 * 2);
  f16*   prod_h  = (f16*)carve(32L * 1024 * 2);
  float* nt_table   = (float*)carve(200L * 4096 * 4);   // gate-interleaved
  float* prod_gates = (float*)carve(32L * 4096 * 4);    // gate-interleaved
  f16*   st_hi   = (f16*)carve(129L * 32 * 32 * 32 * 2);  // [t][cg][b][col]
  f16*   q2      = (f16*)carve(4096L * 2048 * 2);   // query hi|lo (h, then zt)
  f16*   X       = (f16*)carve(4096L * 3072 * 2);   // [h | zt | et] for ct GEMM
  f16*   Y1      = (f16*)carve(4096L * 2048 * 2);   // [mix1 | h]  for zt GEMM
  f16*   Y2      = (f16*)carve(4096L * 2048 * 2);   // [mix2 | zt] for et GEMM
  f16*   ctx_h   = (f16*)carve(32L * 512 * 1024 * 2);
  f16*   ctxT    = (f16*)carve(32L * 1024 * 512 * 2);
  float* scoresP = (float*)carve(4L * 32 * 128 * 512 * 4);  // 4 split-K planes
  f16*   attn    = (f16*)carve(4096L * 512 * 2);
  int*   bar     = (int*)carve(129L * 512 * 4);   // flags [t][cg][bg][wave]
  f16*   Wih_h   = (f16*)X;   // alias: Wih dead before LSTM writes X

  auto f2h = [&](const float* src, f16* dst, long n) {
    long n4 = n / 4;
    k_f2h<<<dim3((unsigned)((n4 + 255) / 256)), dim3(256), 0, stream>>>(src, dst, n4);
  };
  f2h(W_ih, Wih_h, 4096L * 2048);
  f2h(W_hh, Whh_h, 4096L * 1024);
  f2h(Wz,   Wz_h,  1024L * 2048);
  f2h(We,   We_h,  1024L * 2048);
  f2h(Wc,   Wc_h,  1024L * 3072);
  f2h(nt_emb, nte_h, 200L * 1024);
  k_gather_prod<<<dim3(128), dim3(256), 0, stream>>>(rule_emb, init_prod, prod_h);
  // poison h slots 1..128, write h0 into slot 0, zero flags (stream-ordered)
  k_poison<<<dim3(8192), dim3(256), 0, stream>>>(
      (unsigned int*)st_hi + 16384, 128L * 16384);
  k_h0<<<dim3(128), dim3(256), 0, stream>>>(h0, st_hi);
  k_zero<<<dim3(259), dim3(256), 0, stream>>>(bar, 129 * 512);

  auto gemm = [&](const f16* A, long lda, long sA,
                  const f16* B, long ldb, long sB,
                  float* oF, long ldF, long sF, long sSl,
                  f16* oH, long ldH, long sH,
                  f16* oH2, long ldH2, long sH2,
                  f16* o2, long ld2, long s2,
                  const float* b1, const float* b2,
                  int M, int N, int K, int act, int bmod, int zdiv, int ilv,
                  int batch) {
    dim3 grid((unsigned)((M + 127) / 128), (unsigned)((N + 127) / 128),
              (unsigned)(batch * zdiv));
    k_gemm<<<grid, dim3(256), 0, stream>>>(A, lda, sA, B, ldb, sB,
                                           oF, ldF, sF, sSl, oH, ldH, sH,
                                           oH2, ldH2, sH2, o2, ld2, s2,
                                           b1, b2, M, N, K, act, bmod, zdiv, ilv);
  };
  const long SPL = 32L * 128 * 512;   // split-K plane stride (floats)

  // gate tables (gate-interleaved fp32 layout via ilv=1)
  gemm(nte_h, 1024, 0, Wih_h, 2048, 0, nt_table, 4096, 0, 0,
       nullptr,0,0, nullptr,0,0, nullptr,0,0, nullptr, nullptr,
       200, 4096, 1024, 0, 0, 1, 1, 1);
  gemm(prod_h, 1024, 0, Wih_h + 1024, 2048, 0, prod_gates, 4096, 0, 0,
       nullptr,0,0, nullptr,0,0, nullptr,0,0, b_ih, b_hh,
       32, 4096, 1024, 0, 0, 1, 1, 1);

  // persistent LSTM: 64 blocks x 512 threads, flag-gated dataflow
  k_lstm_all<<<dim3(64), dim3(512), 0, stream>>>(
      Whh_h, nt_table, prod_gates, nt_ids, c0, st_hi, q2, X, Y1, bar);

  // --- attention over nl ---
  k_transpose<<<dim3(16, 32, 32), dim3(256), 0, stream>>>(nl, ctxT, ctx_h);
  gemm(q2, 2048, 128L * 2048, ctx_h, 1024, 512L * 1024,
       scoresP, 512, 128L * 512, SPL, nullptr,0,0, nullptr,0,0, nullptr,0,0,
       nullptr, nullptr, 128, 512, 2048, 0, 1024, 4, 0, 32);
  k_softmax4<<<dim3(4096), dim3(256), 0, stream>>>(scoresP, SPL, attn);
  gemm(attn, 512, 128L * 512, ctxT, 512, 1024L * 512,
       nullptr,0,0,0, Y1, 2048, 128L * 2048, nullptr,0,0, nullptr,0,0,
       nullptr, nullptr, 128, 1024, 512, 0, 0, 1, 0, 32);
  // zt = tanh(Y1=[mix1|h] @ Wz^T + bz) -> X[:,1024:2048), Y2[:,1024:2048), q2
  gemm(Y1, 2048, 0, Wz_h, 2048, 0,
       nullptr,0,0,0, X + 1024, 3072, 0, Y2 + 1024, 2048, 0, q2, 2048, 0,
       bz, nullptr, 4096, 1024, 2048, 1, 0, 1, 0, 1);

  // --- attention over env ---
  k_transpose<<<dim3(16, 32, 32), dim3(256), 0, stream>>>(env, ctxT, ctx_h);
  gemm(q2, 2048, 128L * 2048, ctx_h, 1024, 512L * 1024,
       scoresP, 512, 128L * 512, SPL, nullptr,0,0, nullptr,0,0, nullptr,0,0,
       nullptr, nullptr, 128, 512, 2048, 0, 1024, 4, 0, 32);
  k_softmax4<<<dim3(4096), dim3(256), 0, stream>>>(scoresP, SPL, attn);
  gemm(attn, 512, 128L * 512, ctxT, 512, 1024L * 512,
       nullptr,0,0,0, Y2, 2048, 128L * 2048, nullptr,0,0, nullptr,0,0,
       nullptr, nullptr, 128, 1024, 512, 0, 0, 1, 0, 32);
  // et = tanh(Y2=[mix2|zt] @ We^T + be) -> X[:,2048:3072)
  gemm(Y2, 2048, 0, We_h, 2048, 0,
       nullptr,0,0,0, X + 2048, 3072, 0, nullptr,0,0, nullptr,0,0,
       be, nullptr, 4096, 1024, 2048, 1, 0, 1, 0, 1);

  // --- ct = tanh(X=[h|zt|et] @ Wc^T + bc) -> d_out (T,B,H) ---
  gemm(X, 3072, 128L * 3072, Wc_h, 3072, 0,
       out, 32L * 1024, 1024, 0, nullptr,0,0, nullptr,0,0, nullptr,0,0,
       bc, nullptr, 128, 1024, 3072, 1, 0, 1, 0, 32);
}